// Round 7
// baseline (530.284 us; speedup 1.0000x reference)
//
#include <hip/hip_runtime.h>

typedef unsigned short ushort_t;
typedef __bf16 bf16_t;
typedef bf16_t bf16x8 __attribute__((ext_vector_type(8)));
typedef float floatx4 __attribute__((ext_vector_type(4)));
typedef ushort_t ushort4v __attribute__((ext_vector_type(4)));
typedef ushort_t ushort8v __attribute__((ext_vector_type(8)));

static constexpr int B = 2, S = 2048, D = 2048;
static constexpr int H = 16, KVH = 4, HD = 256;

#define DEVFN static __device__ __forceinline__

DEVFN ushort_t f2b(float f) {
  union { float f; unsigned u; } x; x.f = f;
  unsigned r = x.u + 0x7fffu + ((x.u >> 16) & 1u);
  return (ushort_t)(r >> 16);
}
DEVFN float b2f(ushort_t h) {
  union { unsigned u; float f; } x; x.u = ((unsigned)h) << 16;
  return x.f;
}
DEVFN void gll16(const void* g, void* l) {
  __builtin_amdgcn_global_load_lds(
      (const __attribute__((address_space(1))) void*)g,
      (__attribute__((address_space(3))) void*)l, 16, 0, 0);
}

// raw barrier: does NOT drain vmcnt/lgkmcnt (unlike __syncthreads) — the
// counted-vmcnt pipeline depends on loads staying in flight across it.
DEVFN void bar() {
  asm volatile("" ::: "memory");
  __builtin_amdgcn_s_barrier();
  asm volatile("" ::: "memory");
}
template <int N>
DEVFN void waitvm() { asm volatile("s_waitcnt vmcnt(%0)" ::"n"(N) : "memory"); }

// norm + rope one 256-elem row held as 4 elems/lane across a full wave.
DEVFN ushort4v norm_rope_row(ushort4v raw, const float* __restrict__ w,
                             const float* __restrict__ tab, int s, float scale, int lane) {
  float v[4];
  float ss = 0.f;
#pragma unroll
  for (int i = 0; i < 4; i++) { v[i] = b2f(raw[i]); ss += v[i] * v[i]; }
#pragma unroll
  for (int m = 1; m < 64; m <<= 1) ss += __shfl_xor(ss, m, 64);
  const float inv = rsqrtf(ss * (1.0f / HD) + 1e-6f);
  float4 wv = *(const float4*)(w + lane * 4);
  float y[4];
  y[0] = v[0] * inv * (1.0f + wv.x);
  y[1] = v[1] * inv * (1.0f + wv.y);
  y[2] = v[2] * inv * (1.0f + wv.z);
  y[3] = v[3] * inv * (1.0f + wv.w);
  float py[4];
#pragma unroll
  for (int i = 0; i < 4; i++) py[i] = __shfl_xor(y[i], 32, 64);
  const bool lo = (lane < 32);
  ushort4v ov;
#pragma unroll
  for (int i = 0; i < 4; i++) {
    int dd = (lane * 4 + i) & 127;
    float2 cs = *(const float2*)(tab + ((size_t)s * 128 + dd) * 2);
    float rot = lo ? -py[i] : py[i];
    ov[i] = f2b((y[i] * cs.x + rot * cs.y) * scale);
  }
  return ov;
}

// ---------------------------------------------------------------- conversions
__global__ void k_cvt_bf16(const float* __restrict__ in, ushort_t* __restrict__ out, int n) {
  int i = (blockIdx.x * 256 + threadIdx.x) * 4;
  if (i >= n) return;
  float4 v = *(const float4*)(in + i);
  ushort4v o;
  o[0] = f2b(v.x); o[1] = f2b(v.y); o[2] = f2b(v.z); o[3] = f2b(v.w);
  *(ushort4v*)(out + i) = o;
}

// in: R x C fp32 row-major; out: C x R bf16 row-major. 64x64 tiles.
__global__ void k_transpose_cvt(const float* __restrict__ in, ushort_t* __restrict__ out,
                                int R, int C) {
  __shared__ float tile[64][65];
  const int cb = blockIdx.x * 64, rb = blockIdx.y * 64;
  const int t = threadIdx.x;
  const int l16 = t & 15, g16 = t >> 4;
#pragma unroll
  for (int p = 0; p < 4; p++) {
    const int r = p * 16 + g16;
    float4 v = *(const float4*)(in + (size_t)(rb + r) * C + cb + l16 * 4);
    tile[r][l16 * 4 + 0] = v.x;
    tile[r][l16 * 4 + 1] = v.y;
    tile[r][l16 * 4 + 2] = v.z;
    tile[r][l16 * 4 + 3] = v.w;
  }
  __syncthreads();
#pragma unroll
  for (int p = 0; p < 4; p++) {
    const int c = p * 16 + g16;
    ushort4v o4;
#pragma unroll
    for (int i = 0; i < 4; i++) o4[i] = f2b(tile[l16 * 4 + i][c]);
    *(ushort4v*)(out + (size_t)(cb + c) * R + rb + l16 * 4) = o4;
  }
}

// cos/sin table: tab[(s*128+dd)*2] = cos, +1 = sin
__global__ void k_rope_table(const int* __restrict__ pos_ids, float* __restrict__ tab) {
  int idx = blockIdx.x * 256 + threadIdx.x;  // S*128 total
  int s = idx >> 7, dd = idx & 127;
  float ang = (float)pos_ids[s] * exp2f((float)dd * (-13.287712379549449f / 128.0f));
  tab[idx * 2] = cosf(ang);
  tab[idx * 2 + 1] = sinf(ang);
}

// ---------------------------------------------------------------- 128x256 pipelined GEMM
// (unchanged from round 2 — see comments there)
DEVFN void stage_tile(const ushort_t* __restrict__ A, const ushort_t* __restrict__ Bt,
                      ushort_t* smb, size_t arow0, size_t brow0, int K, int kt) {
  const int t = threadIdx.x;
  const int rq = t >> 2;            // 0..127
  const int cq = (t & 3) * 8;       // col quarter within 32
#pragma unroll
  for (int i = 0; i < 2; i++) {     // A: [ks=i][128][32], 16 KiB
    const int cs = cq ^ ((rq & 8) << 1);
    gll16(A + (arow0 + rq) * (size_t)K + kt + i * 32 + cs, smb + i * 4096 + t * 8);
  }
#pragma unroll
  for (int i = 0; i < 4; i++) {     // B: [ks=i>>1][256][32], 32 KiB
    const int row = ((i & 1) << 7) | rq;
    const int cs = cq ^ ((row & 8) << 1);
    gll16(Bt + (brow0 + row) * (size_t)K + kt + (i >> 1) * 32 + cs,
          smb + 8192 + i * 4096 + t * 8);
  }
}

DEVFN bf16x8 ldsA(const ushort_t* buf, int row, int ks, int lq) {
  const int c = (lq * 8) ^ ((row & 8) << 1);
  return *(const bf16x8*)(buf + ks * 4096 + row * 32 + c);
}
DEVFN bf16x8 ldsB(const ushort_t* buf, int row, int ks, int lq) {
  const int c = (lq * 8) ^ ((row & 8) << 1);
  return *(const bf16x8*)(buf + 8192 + ks * 8192 + row * 32 + c);
}

template <int MODE>
__global__ __launch_bounds__(512, 2)
void k_gemm256(const ushort_t* __restrict__ A, const ushort_t* __restrict__ Bt,
               void* __restrict__ C0, void* __restrict__ C1, void* __restrict__ C2,
               int N, int K) {
  __shared__ ushort_t sm[49152];  // 96 KiB: buf[t&1]*24576 { A:8192, B:16384 }
  const int tid = threadIdx.x;
  const int lane = tid & 63, wave = tid >> 6;
  const int lr = lane & 15, lq = lane >> 4;
  const int wm = wave >> 2, wn = wave & 3;
  const size_t m0 = (size_t)blockIdx.x * 128;
  const size_t n0 = (size_t)blockIdx.y * 256;

  floatx4 acc[4][4];
#pragma unroll
  for (int i = 0; i < 4; i++)
#pragma unroll
    for (int j = 0; j < 4; j++) acc[i][j] = {0.f, 0.f, 0.f, 0.f};

  const int NT = K >> 6;
  stage_tile(A, Bt, sm, m0, n0, K, 0);
  stage_tile(A, Bt, sm + 24576, m0, n0, K, 64);

  for (int t = 0; t < NT; ++t) {
    ushort_t* bA = sm + (t & 1) * 24576;
    if (t < NT - 1) waitvm<6>(); else waitvm<0>();
    bar();  // all waves' stage(t) landed

    bf16x8 a[2][4], bfr[2][4];
#pragma unroll
    for (int ks = 0; ks < 2; ks++) {
#pragma unroll
      for (int m = 0; m < 4; m++) a[ks][m] = ldsA(bA, wm * 64 + m * 16 + lr, ks, lq);
#pragma unroll
      for (int n = 0; n < 4; n++) bfr[ks][n] = ldsB(bA, wn * 64 + n * 16 + lr, ks, lq);
    }
    __builtin_amdgcn_s_setprio(1);
#pragma unroll
    for (int m = 0; m < 4; m++)
#pragma unroll
      for (int n = 0; n < 4; n++)
        acc[m][n] = __builtin_amdgcn_mfma_f32_16x16x32_bf16(a[0][m], bfr[0][n], acc[m][n], 0, 0, 0);
    __builtin_amdgcn_s_setprio(0);
    asm volatile("s_waitcnt lgkmcnt(0)" ::: "memory");
    __builtin_amdgcn_sched_barrier(0);
    bar();  // all waves done reading buf[t&1] -> safe to overwrite
    if (t + 2 < NT) stage_tile(A, Bt, bA, m0, n0, K, (t + 2) * 64);
    __builtin_amdgcn_sched_barrier(0);  // keep staging issue ahead of ks1 MFMAs
    __builtin_amdgcn_s_setprio(1);
#pragma unroll
    for (int m = 0; m < 4; m++)
#pragma unroll
      for (int n = 0; n < 4; n++)
        acc[m][n] = __builtin_amdgcn_mfma_f32_16x16x32_bf16(a[1][m], bfr[1][n], acc[m][n], 0, 0, 0);
    __builtin_amdgcn_s_setprio(0);
  }

  const int colb = (int)n0;  // block-uniform: region boundaries are multiples of 256
#pragma unroll
  for (int mg = 0; mg < 4; mg++)
#pragma unroll
    for (int ng = 0; ng < 4; ng++) {
      const size_t row0 = m0 + wm * 64 + mg * 16 + lq * 4;
      const int col = colb + wn * 64 + ng * 16 + lr;
      if (MODE == 1) {
#pragma unroll
        for (int r = 0; r < 4; r++)
          ((float*)C0)[(row0 + r) * N + col] = acc[mg][ng][r];
      } else {
        if (colb < 4096) {  // Q
#pragma unroll
        for (int r = 0; r < 4; r++)
            ((ushort_t*)C0)[(row0 + r) * 4096 + col] = f2b(acc[mg][ng][r]);
        } else if (colb < 5120) {  // K row-major (ld 1024)
#pragma unroll
          for (int r = 0; r < 4; r++)
            ((ushort_t*)C1)[(row0 + r) * 1024 + (col - 4096)] = f2b(acc[mg][ng][r]);
        } else {  // V -> 64-row MFMA-fragment-chunk layout
          const int ch = col - 5120;
          const int kvh = ch >> 8, chh = ch & 255, f = chh >> 4, lrv = chh & 15;
          const size_t bb = row0 >> 11;
          const int s0 = (int)(row0 & 2047);
          const int tile = s0 >> 6, kh = (s0 >> 5) & 1, lqv = (s0 >> 3) & 3, j0 = s0 & 7;
          ushort4v pk;
#pragma unroll
          for (int r = 0; r < 4; r++) pk[r] = f2b(acc[mg][ng][r]);
          *(ushort4v*)&((ushort_t*)C2)[((bb * KVH + kvh) * (S / 64) + tile) * 16384 +
                                       (size_t)(f * 2 + kh) * 512 +
                                       (size_t)(lqv * 16 + lrv) * 8 + j0] = pk;
        }
      }
    }
}

// ---------------------------------------------------------------- RMSNorm + RoPE + swizzle (K)
__global__ void k_norm_rope_k(const ushort_t* __restrict__ Kb, ushort_t* __restrict__ Kf,
                              const float* __restrict__ w, const float* __restrict__ tab) {
  __shared__ ushort_t t[64 * 264];  // rows padded +8
  const int lane = threadIdx.x & 63, wave = threadIdx.x >> 6;
  const int tile = blockIdx.x, kvh = blockIdx.y, b = blockIdx.z;
#pragma unroll
  for (int rr = 0; rr < 16; rr++) {
    const int row = wave * 16 + rr;
    const int s = tile * 64 + row;
    const ushort_t* p = Kb + ((size_t)(b * S + s) * KVH + kvh) * HD + lane * 4;
    ushort4v raw = *(const ushort4v*)p;
    *(ushort4v*)&t[row * 264 + lane * 4] = norm_rope_row(raw, w, tab, s, 1.0f, lane);
  }
  __syncthreads();
  ushort_t* dst = Kf + ((size_t)(b * KVH + kvh) * (S / 64) + tile) * 16384;
  const int lr = lane & 15, lq = lane >> 4;
#pragma unroll
  for (int q = 0; q < 8; q++) {
    const int c = wave * 8 + q;  // chunk, wave-uniform
    const int nt = c >> 3, ks = c & 7;
    ushort8v v = *(const ushort8v*)&t[(nt * 16 + lr) * 264 + ks * 32 + lq * 8];
    *(ushort8v*)&dst[(size_t)c * 512 + lane * 8] = v;
  }
}

// ---------------------------------------------------------------- flash attention
// 1-D grid 512 blocks, 256 thr = 4 waves x 16 q-rows (64-row q-tile).
// XCD remap: lin%8 selects (b,kvh) -> each XCD's L2 holds its own 2MB KV slice.
// Block does q-tiles {31-xq, xq} -> uniform 33 kv-tiles. 74.75KB LDS -> 2
// blocks/CU (inter-block overlap) + 2-barrier counted-vmcnt pipeline (r6's
// 4-barrier version was 20% STALL-heavier — barriers cost more than staging
// latency here):
//   QK(Ks) -> softmax -> P-store -> lgkm0 -> waitvm0[V(kt); covered by
//   QK+softmax] -> BAR1{Ks free & Vs valid} -> stage K(kt+1) -> PV(Vs) ->
//   lgkm0 -> waitvm0[K(kt+1); covered by PV] -> BAR2{Vs free & Ks valid}
//   -> stage V(kt+1)
// Q RMSNorm+RoPE fused into the Q-load; rotate-half partner qf[ks^4] is
// lane-local; row-sum = 2 shuffles. Staged under the prologue K/V flight.
__global__ __launch_bounds__(256, 2)
void k_attn(const ushort_t* __restrict__ Q, const ushort_t* __restrict__ Kf,
            const ushort_t* __restrict__ Vf, ushort_t* __restrict__ O,
            const float* __restrict__ qw, const float* __restrict__ tab) {
  __shared__ ushort_t Ks[16384];      // chunks c = nt*8+ks, nt 0..3
  __shared__ ushort_t Vs[16384];      // chunks (f*2+kh), f 0..15, kh 0..1
  __shared__ ushort_t Ps[4][16 * 72]; // per-wave P 16x64, row stride 72
  const int lane = threadIdx.x & 63, wave = threadIdx.x >> 6;
  const int lr = lane & 15, lq = lane >> 4;
  const int lin = blockIdx.x;          // 0..511
  const int g = lin & 7, j = lin >> 3; // g -> XCD -> (b,kvh); j 0..63
  const int b = g >> 2, kvh = g & 3;
  const int h = kvh * 4 + (j >> 4);
  const int xq = j & 15;
  const size_t kvb = (size_t)(b * KVH + kvh) * (S / 64);

#pragma unroll 1
  for (int half = 0; half < 2; half++) {
    const int qt = half ? xq : (S / 64 - 1 - xq);
    const int q0 = qt * 64 + wave * 16;
    const int sq = q0 + lr;
    const int ntiles = qt + 1;

    // ---- prologue: stage K(0), V(0) (8+8 gll16/wave)
    {
      const ushort_t* tb = Kf + kvb * 16384;
      const ushort_t* vb = Vf + kvb * 16384;
#pragma unroll
      for (int i = 0; i < 8; i++) {
        const int c = wave * 8 + i;
        gll16(tb + (size_t)c * 512 + lane * 8, &Ks[c * 512 + lane * 8]);
      }
#pragma unroll
      for (int i = 0; i < 8; i++) {
        const int c = wave * 8 + i;
        gll16(vb + (size_t)c * 512 + lane * 8, &Vs[c * 512 + lane * 8]);
      }
    }

    // ---- fused RMSNorm + RoPE Q-load (overlaps staging flight)
    bf16x8 qf[8];
    {
      const ushort_t* qp = Q + ((size_t)(b * S + sq) * H + h) * HD + lq * 8;
      ushort8v qr[8];
#pragma unroll
      for (int ks = 0; ks < 8; ks++) qr[ks] = *(const ushort8v*)(qp + ks * 32);
      float ss = 0.f;
#pragma unroll
      for (int ks = 0; ks < 8; ks++)
#pragma unroll
        for (int jj = 0; jj < 8; jj++) { float v = b2f(qr[ks][jj]); ss += v * v; }
      ss += __shfl_xor(ss, 16, 64);
      ss += __shfl_xor(ss, 32, 64);
      const float inv = rsqrtf(ss * (1.0f / HD) + 1e-6f);
      const float sc = 0.0625f * 1.4426950408889634f;  // 1/sqrt(HD) * log2(e)
#pragma unroll
      for (int c = 0; c < 4; c++) {
        const int d0 = c * 32 + lq * 8;  // 0..127
        float wl[8], wh[8];
        {
          float4 a0 = *(const float4*)(qw + d0);
          float4 a1 = *(const float4*)(qw + d0 + 4);
          float4 a2 = *(const float4*)(qw + d0 + 128);
          float4 a3 = *(const float4*)(qw + d0 + 132);
          wl[0]=a0.x; wl[1]=a0.y; wl[2]=a0.z; wl[3]=a0.w;
          wl[4]=a1.x; wl[5]=a1.y; wl[6]=a1.z; wl[7]=a1.w;
          wh[0]=a2.x; wh[1]=a2.y; wh[2]=a2.z; wh[3]=a2.w;
          wh[4]=a3.x; wh[5]=a3.y; wh[6]=a3.z; wh[7]=a3.w;
        }
        const float* tp = tab + ((size_t)sq * 128 + d0) * 2;
        ushort8v olo, ohi;
#pragma unroll
        for (int jj = 0; jj < 8; jj++) {
          float ylo = b2f(qr[c][jj]) * inv * (1.0f + wl[jj]);
          float yhi = b2f(qr[c + 4][jj]) * inv * (1.0f + wh[jj]);
          float2 cs = *(const float2*)(tp + jj * 2);
          olo[jj] = f2b((ylo * cs.x - yhi * cs.y) * sc);
          ohi[jj] = f2b((yhi * cs.x + ylo * cs.y) * sc);
        }
        qf[c] = *reinterpret_cast<bf16x8*>(&olo);
        qf[c + 4] = *reinterpret_cast<bf16x8*>(&ohi);
      }
    }

    floatx4 o[16];
#pragma unroll
    for (int f = 0; f < 16; f++) o[f] = {0.f, 0.f, 0.f, 0.f};
    float m_i[4] = {-1e30f, -1e30f, -1e30f, -1e30f};
    float l_i[4] = {0.f, 0.f, 0.f, 0.f};

    waitvm<8>();  // own K(0) landed (V(0)'s 8 loads stay in flight)
    bar();        // all waves' K(0) landed -> Ks valid

    for (int kt = 0; kt < ntiles; kt++) {
      const int kbase = kt * 64;
      const bool last = (kt == ntiles - 1);

      // ---- QK^T on Ks (valid by loop invariant)
      const int ntmax = min(4, ((q0 + 15 - kbase) >> 4) + 1);  // >= 1 always
      floatx4 sacc[4];
      __builtin_amdgcn_s_setprio(1);
#pragma unroll
      for (int nt = 0; nt < 4; nt++) {
        if (nt < ntmax) {
          sacc[nt] = {0.f, 0.f, 0.f, 0.f};
#pragma unroll
          for (int ks = 0; ks < 8; ks++) {
            bf16x8 kf = *(const bf16x8*)&Ks[(nt * 8 + ks) * 512 + lane * 8];
            sacc[nt] = __builtin_amdgcn_mfma_f32_16x16x32_bf16(qf[ks], kf, sacc[nt], 0, 0, 0);
          }
        } else {
          sacc[nt] = {-1e30f, -1e30f, -1e30f, -1e30f};
        }
      }
      __builtin_amdgcn_s_setprio(0);

      if (kbase + 63 > q0) {  // causal mask on diagonal tiles
#pragma unroll
        for (int nt = 0; nt < 4; nt++)
          if (nt < ntmax)
#pragma unroll
            for (int r = 0; r < 4; r++)
              if (kbase + nt * 16 + lr > q0 + lq * 4 + r) sacc[nt][r] = -1e30f;
      }
      // ---- online softmax (VALU — covers the V(kt) flight)
      float mt[4], alpha[4], rs[4];
#pragma unroll
      for (int r = 0; r < 4; r++)
        mt[r] = fmaxf(fmaxf(sacc[0][r], sacc[1][r]), fmaxf(sacc[2][r], sacc[3][r]));
#pragma unroll
      for (int m = 1; m < 16; m <<= 1)
#pragma unroll
        for (int r = 0; r < 4; r++) mt[r] = fmaxf(mt[r], __shfl_xor(mt[r], m, 64));
#pragma unroll
      for (int r = 0; r < 4; r++) {
        float mn = fmaxf(m_i[r], mt[r]);
        alpha[r] = exp2f(m_i[r] - mn);
        m_i[r] = mn;
      }
#pragma unroll
      for (int nt = 0; nt < 4; nt++)
#pragma unroll
        for (int r = 0; r < 4; r++) sacc[nt][r] = exp2f(sacc[nt][r] - m_i[r]);
#pragma unroll
      for (int r = 0; r < 4; r++)
        rs[r] = (sacc[0][r] + sacc[1][r]) + (sacc[2][r] + sacc[3][r]);
#pragma unroll
      for (int m = 1; m < 16; m <<= 1)
#pragma unroll
        for (int r = 0; r < 4; r++) rs[r] += __shfl_xor(rs[r], m, 64);
#pragma unroll
      for (int r = 0; r < 4; r++) l_i[r] = l_i[r] * alpha[r] + rs[r];
      if (__any((alpha[0] < 1.f) | (alpha[1] < 1.f) | (alpha[2] < 1.f) | (alpha[3] < 1.f))) {
#pragma unroll
        for (int f = 0; f < 16; f++) {
          o[f][0] *= alpha[0]; o[f][1] *= alpha[1];
          o[f][2] *= alpha[2]; o[f][3] *= alpha[3];
        }
      }
      // ---- P -> bf16 via per-wave LDS round-trip
      ushort_t* psw = Ps[wave];
#pragma unroll
      for (int nt = 0; nt < 4; nt++)
#pragma unroll
        for (int r = 0; r < 4; r++)
          psw[(lq * 4 + r) * 72 + nt * 16 + lr] = f2b(sacc[nt][r]);
      bf16x8 pf0 = *(const bf16x8*)&psw[lr * 72 + lq * 8];
      bf16x8 pf1 = *(const bf16x8*)&psw[lr * 72 + 32 + lq * 8];

      asm volatile("s_waitcnt lgkmcnt(0)" ::: "memory");  // own Ks reads + Ps round-trip done
      __builtin_amdgcn_sched_barrier(0);
      waitvm<0>();  // own V(kt) landed (flight covered by QK+softmax)
      bar();        // BAR1: global {Ks free to overwrite, Vs valid}

      if (!last) {  // stage K(kt+1); flight covered by PV below
        const ushort_t* tb = Kf + (kvb + kt + 1) * 16384;
#pragma unroll
        for (int i = 0; i < 8; i++) {
          const int c = wave * 8 + i;
          gll16(tb + (size_t)c * 512 + lane * 8, &Ks[c * 512 + lane * 8]);
        }
      }

      // ---- PV on Vs
      __builtin_amdgcn_s_setprio(1);
#pragma unroll
      for (int f = 0; f < 16; f++) {
        bf16x8 vf0 = *(const bf16x8*)&Vs[(f * 2 + 0) * 512 + lane * 8];
        o[f] = __builtin_amdgcn_mfma_f32_16x16x32_bf16(pf0, vf0, o[f], 0, 0, 0);
        bf16x8 vf1 = *(const bf16x8*)&Vs[(f * 2 + 1) * 512 + lane * 8];
        o[f] = __builtin_amdgcn_mfma_f32_16x16x32_bf16(pf1, vf1, o[f], 0, 0, 0);
      }
      __builtin_amdgcn_s_setprio(0);

      asm volatile("s_waitcnt lgkmcnt(0)" ::: "memory");  // own Vs reads done
      __builtin_amdgcn_sched_barrier(0);
      waitvm<0>();  // own K(kt+1) landed (flight covered by PV)
      bar();        // BAR2: global {Vs free to overwrite, Ks valid for next iter}

      if (!last) {  // stage V(kt+1); flight covered by next QK+softmax
        const ushort_t* vb = Vf + (kvb + kt + 1) * 16384;
#pragma unroll
        for (int i = 0; i < 8; i++) {
          const int c = wave * 8 + i;
          gll16(vb + (size_t)c * 512 + lane * 8, &Vs[c * 512 + lane * 8]);
        }
      }
    }
    // BAR2 of the last iteration guarantees all LDS reads done -> next half's
    // prologue staging is overwrite-safe; O-write touches only global memory.
    float invl[4];
#pragma unroll
    for (int r = 0; r < 4; r++) invl[r] = 1.0f / l_i[r];
#pragma unroll
    for (int f = 0; f < 16; f++)
#pragma unroll
      for (int r = 0; r < 4; r++)
        O[((size_t)(b * S + q0 + lq * 4 + r) * H + h) * HD + f * 16 + lr] =
            f2b(o[f][r] * invl[r]);
  }
}

// ---------------------------------------------------------------- launch
extern "C" void kernel_launch(void* const* d_in, const int* in_sizes, int n_in,
                              void* d_out, int out_size, void* d_ws, size_t ws_size,
                              hipStream_t stream) {
  const float* hs = (const float*)d_in[0];
  const float* Wq = (const float*)d_in[1];
  const float* Wk = (const float*)d_in[2];
  const float* Wv = (const float*)d_in[3];
  const float* Wo = (const float*)d_in[4];
  const float* qw = (const float*)d_in[5];
  const float* kw = (const float*)d_in[6];
  const int* pos = (const int*)d_in[7];
  float* out = (float*)d_out;

  char* ws = (char*)d_ws;
  size_t off = 0;
  auto alloc = [&](size_t bytes) {
    void* p = ws + off;
    off += (bytes + 255) & ~(size_t)255;
    return p;
  };
  ushort_t* Xb   = (ushort_t*)alloc((size_t)B * S * D * 2);
  // Wqt and Wkvt MUST stay adjacent: fused QKV GEMM treats them as one
  // 6144 x 2048 Bt matrix (Wq^T rows [0,4096), Wk^T [4096,5120), Wv^T [5120,6144)).
  ushort_t* Wqt  = (ushort_t*)alloc((size_t)(H * HD) * D * 2);
  ushort_t* Wkvt = (ushort_t*)alloc((size_t)(2 * KVH * HD) * D * 2);
  ushort_t* Wot  = (ushort_t*)alloc((size_t)D * (H * HD) * 2);
  ushort_t* Qb   = (ushort_t*)alloc((size_t)B * S * H * HD * 2);
  ushort_t* Kf   = (ushort_t*)alloc((size_t)B * S * KVH * HD * 2);
  ushort_t* Vf   = (ushort_t*)alloc((size_t)B * S * KVH * HD * 2);
  ushort_t* Ab   = (ushort_t*)alloc((size_t)B * S * H * HD * 2);
  float*    tab  = (float*)alloc((size_t)S * 128 * 2 * sizeof(float));
  ushort_t* Kb = Ab;  // aliased: consumed by k_norm_rope_k before k_attn writes Ab

  k_cvt_bf16<<<(B * S * D / 4 + 255) / 256, 256, 0, stream>>>(hs, Xb, B * S * D);
  k_transpose_cvt<<<dim3((H * HD) / 64, D / 64), 256, 0, stream>>>(Wq, Wqt, D, H * HD);
  k_transpose_cvt<<<dim3((KVH * HD) / 64, D / 64), 256, 0, stream>>>(Wk, Wkvt, D, KVH * HD);
  k_transpose_cvt<<<dim3((KVH * HD) / 64, D / 64), 256, 0, stream>>>(
      Wv, Wkvt + (size_t)(KVH * HD) * D, D, KVH * HD);
  k_transpose_cvt<<<dim3(D / 64, (H * HD) / 64), 256, 0, stream>>>(Wo, Wot, H * HD, D);
  k_rope_table<<<S * 128 / 256, 256, 0, stream>>>(pos, tab);

  // fused Q+K+V projection: N = 4096 + 1024 + 1024 = 6144; 32x24 = 768 blocks = 3 exact rounds
  k_gemm256<0><<<dim3((B * S) / 128, 6144 / 256), 512, 0, stream>>>(
      Xb, Wqt, Qb, Kb, Vf, 6144, D);

  k_norm_rope_k<<<dim3(S / 64, KVH, B), 256, 0, stream>>>(Kb, Kf, kw, tab);

  // Q norm+rope fused into k_attn; 512 blocks = exactly one round at 2 blocks/CU
  k_attn<<<512, 256, 0, stream>>>(Qb, Kf, Vf, Ab, qw, tab);

  // O-projection: 32x8 = 256 blocks = exactly one full round
  k_gemm256<1><<<dim3((B * S) / 128, D / 256), 512, 0, stream>>>(
      Ab, Wot, out, nullptr, nullptr, D, H * HD);
}

// Round 8
// 505.110 us; speedup vs baseline: 1.0498x; 1.0498x over previous
//
#include <hip/hip_runtime.h>

typedef unsigned short ushort_t;
typedef __bf16 bf16_t;
typedef bf16_t bf16x8 __attribute__((ext_vector_type(8)));
typedef float floatx4 __attribute__((ext_vector_type(4)));
typedef ushort_t ushort4v __attribute__((ext_vector_type(4)));
typedef ushort_t ushort8v __attribute__((ext_vector_type(8)));

static constexpr int B = 2, S = 2048, D = 2048;
static constexpr int H = 16, KVH = 4, HD = 256;

#define DEVFN static __device__ __forceinline__

DEVFN ushort_t f2b(float f) {
  union { float f; unsigned u; } x; x.f = f;
  unsigned r = x.u + 0x7fffu + ((x.u >> 16) & 1u);
  return (ushort_t)(r >> 16);
}
DEVFN float b2f(ushort_t h) {
  union { unsigned u; float f; } x; x.u = ((unsigned)h) << 16;
  return x.f;
}
DEVFN void gll16(const void* g, void* l) {
  __builtin_amdgcn_global_load_lds(
      (const __attribute__((address_space(1))) void*)g,
      (__attribute__((address_space(3))) void*)l, 16, 0, 0);
}

// raw barrier (GEMM pipeline only): does NOT drain vmcnt/lgkmcnt.
DEVFN void bar() {
  asm volatile("" ::: "memory");
  __builtin_amdgcn_s_barrier();
  asm volatile("" ::: "memory");
}
template <int N>
DEVFN void waitvm() { asm volatile("s_waitcnt vmcnt(%0)" ::"n"(N) : "memory"); }

// norm + rope one 256-elem row held as 4 elems/lane across a full wave.
DEVFN ushort4v norm_rope_row(ushort4v raw, const float* __restrict__ w,
                             const float* __restrict__ tab, int s, float scale, int lane) {
  float v[4];
  float ss = 0.f;
#pragma unroll
  for (int i = 0; i < 4; i++) { v[i] = b2f(raw[i]); ss += v[i] * v[i]; }
#pragma unroll
  for (int m = 1; m < 64; m <<= 1) ss += __shfl_xor(ss, m, 64);
  const float inv = rsqrtf(ss * (1.0f / HD) + 1e-6f);
  float4 wv = *(const float4*)(w + lane * 4);
  float y[4];
  y[0] = v[0] * inv * (1.0f + wv.x);
  y[1] = v[1] * inv * (1.0f + wv.y);
  y[2] = v[2] * inv * (1.0f + wv.z);
  y[3] = v[3] * inv * (1.0f + wv.w);
  float py[4];
#pragma unroll
  for (int i = 0; i < 4; i++) py[i] = __shfl_xor(y[i], 32, 64);
  const bool lo = (lane < 32);
  ushort4v ov;
#pragma unroll
  for (int i = 0; i < 4; i++) {
    int dd = (lane * 4 + i) & 127;
    float2 cs = *(const float2*)(tab + ((size_t)s * 128 + dd) * 2);
    float rot = lo ? -py[i] : py[i];
    ov[i] = f2b((y[i] * cs.x + rot * cs.y) * scale);
  }
  return ov;
}

// ---------------------------------------------------------------- conversions
__global__ void k_cvt_bf16(const float* __restrict__ in, ushort_t* __restrict__ out, int n) {
  int i = (blockIdx.x * 256 + threadIdx.x) * 4;
  if (i >= n) return;
  float4 v = *(const float4*)(in + i);
  ushort4v o;
  o[0] = f2b(v.x); o[1] = f2b(v.y); o[2] = f2b(v.z); o[3] = f2b(v.w);
  *(ushort4v*)(out + i) = o;
}

// in: R x C fp32 row-major; out: C x R bf16 row-major. 64x64 tiles.
__global__ void k_transpose_cvt(const float* __restrict__ in, ushort_t* __restrict__ out,
                                int R, int C) {
  __shared__ float tile[64][65];
  const int cb = blockIdx.x * 64, rb = blockIdx.y * 64;
  const int t = threadIdx.x;
  const int l16 = t & 15, g16 = t >> 4;
#pragma unroll
  for (int p = 0; p < 4; p++) {
    const int r = p * 16 + g16;
    float4 v = *(const float4*)(in + (size_t)(rb + r) * C + cb + l16 * 4);
    tile[r][l16 * 4 + 0] = v.x;
    tile[r][l16 * 4 + 1] = v.y;
    tile[r][l16 * 4 + 2] = v.z;
    tile[r][l16 * 4 + 3] = v.w;
  }
  __syncthreads();
#pragma unroll
  for (int p = 0; p < 4; p++) {
    const int c = p * 16 + g16;
    ushort4v o4;
#pragma unroll
    for (int i = 0; i < 4; i++) o4[i] = f2b(tile[l16 * 4 + i][c]);
    *(ushort4v*)(out + (size_t)(cb + c) * R + rb + l16 * 4) = o4;
  }
}

// cos/sin table: tab[(s*128+dd)*2] = cos, +1 = sin
__global__ void k_rope_table(const int* __restrict__ pos_ids, float* __restrict__ tab) {
  int idx = blockIdx.x * 256 + threadIdx.x;  // S*128 total
  int s = idx >> 7, dd = idx & 127;
  float ang = (float)pos_ids[s] * exp2f((float)dd * (-13.287712379549449f / 128.0f));
  tab[idx * 2] = cosf(ang);
  tab[idx * 2 + 1] = sinf(ang);
}

// ---------------------------------------------------------------- 128x256 pipelined GEMM
// (unchanged from round 2 — see comments there)
DEVFN void stage_tile(const ushort_t* __restrict__ A, const ushort_t* __restrict__ Bt,
                      ushort_t* smb, size_t arow0, size_t brow0, int K, int kt) {
  const int t = threadIdx.x;
  const int rq = t >> 2;            // 0..127
  const int cq = (t & 3) * 8;       // col quarter within 32
#pragma unroll
  for (int i = 0; i < 2; i++) {     // A: [ks=i][128][32], 16 KiB
    const int cs = cq ^ ((rq & 8) << 1);
    gll16(A + (arow0 + rq) * (size_t)K + kt + i * 32 + cs, smb + i * 4096 + t * 8);
  }
#pragma unroll
  for (int i = 0; i < 4; i++) {     // B: [ks=i>>1][256][32], 32 KiB
    const int row = ((i & 1) << 7) | rq;
    const int cs = cq ^ ((row & 8) << 1);
    gll16(Bt + (brow0 + row) * (size_t)K + kt + (i >> 1) * 32 + cs,
          smb + 8192 + i * 4096 + t * 8);
  }
}

DEVFN bf16x8 ldsA(const ushort_t* buf, int row, int ks, int lq) {
  const int c = (lq * 8) ^ ((row & 8) << 1);
  return *(const bf16x8*)(buf + ks * 4096 + row * 32 + c);
}
DEVFN bf16x8 ldsB(const ushort_t* buf, int row, int ks, int lq) {
  const int c = (lq * 8) ^ ((row & 8) << 1);
  return *(const bf16x8*)(buf + 8192 + ks * 8192 + row * 32 + c);
}

template <int MODE>
__global__ __launch_bounds__(512, 2)
void k_gemm256(const ushort_t* __restrict__ A, const ushort_t* __restrict__ Bt,
               void* __restrict__ C0, void* __restrict__ C1, void* __restrict__ C2,
               int N, int K) {
  __shared__ ushort_t sm[49152];  // 96 KiB: buf[t&1]*24576 { A:8192, B:16384 }
  const int tid = threadIdx.x;
  const int lane = tid & 63, wave = tid >> 6;
  const int lr = lane & 15, lq = lane >> 4;
  const int wm = wave >> 2, wn = wave & 3;
  const size_t m0 = (size_t)blockIdx.x * 128;
  const size_t n0 = (size_t)blockIdx.y * 256;

  floatx4 acc[4][4];
#pragma unroll
  for (int i = 0; i < 4; i++)
#pragma unroll
    for (int j = 0; j < 4; j++) acc[i][j] = {0.f, 0.f, 0.f, 0.f};

  const int NT = K >> 6;
  stage_tile(A, Bt, sm, m0, n0, K, 0);
  stage_tile(A, Bt, sm + 24576, m0, n0, K, 64);

  for (int t = 0; t < NT; ++t) {
    ushort_t* bA = sm + (t & 1) * 24576;
    if (t < NT - 1) waitvm<6>(); else waitvm<0>();
    bar();  // all waves' stage(t) landed

    bf16x8 a[2][4], bfr[2][4];
#pragma unroll
    for (int ks = 0; ks < 2; ks++) {
#pragma unroll
      for (int m = 0; m < 4; m++) a[ks][m] = ldsA(bA, wm * 64 + m * 16 + lr, ks, lq);
#pragma unroll
      for (int n = 0; n < 4; n++) bfr[ks][n] = ldsB(bA, wn * 64 + n * 16 + lr, ks, lq);
    }
    __builtin_amdgcn_s_setprio(1);
#pragma unroll
    for (int m = 0; m < 4; m++)
#pragma unroll
      for (int n = 0; n < 4; n++)
        acc[m][n] = __builtin_amdgcn_mfma_f32_16x16x32_bf16(a[0][m], bfr[0][n], acc[m][n], 0, 0, 0);
    __builtin_amdgcn_s_setprio(0);
    asm volatile("s_waitcnt lgkmcnt(0)" ::: "memory");
    __builtin_amdgcn_sched_barrier(0);
    bar();  // all waves done reading buf[t&1] -> safe to overwrite
    if (t + 2 < NT) stage_tile(A, Bt, bA, m0, n0, K, (t + 2) * 64);
    __builtin_amdgcn_sched_barrier(0);  // keep staging issue ahead of ks1 MFMAs
    __builtin_amdgcn_s_setprio(1);
#pragma unroll
    for (int m = 0; m < 4; m++)
#pragma unroll
      for (int n = 0; n < 4; n++)
        acc[m][n] = __builtin_amdgcn_mfma_f32_16x16x32_bf16(a[1][m], bfr[1][n], acc[m][n], 0, 0, 0);
    __builtin_amdgcn_s_setprio(0);
  }

  const int colb = (int)n0;  // block-uniform: region boundaries are multiples of 256
#pragma unroll
  for (int mg = 0; mg < 4; mg++)
#pragma unroll
    for (int ng = 0; ng < 4; ng++) {
      const size_t row0 = m0 + wm * 64 + mg * 16 + lq * 4;
      const int col = colb + wn * 64 + ng * 16 + lr;
      if (MODE == 1) {
#pragma unroll
        for (int r = 0; r < 4; r++)
          ((float*)C0)[(row0 + r) * N + col] = acc[mg][ng][r];
      } else {
        if (colb < 4096) {  // Q
#pragma unroll
          for (int r = 0; r < 4; r++)
            ((ushort_t*)C0)[(row0 + r) * 4096 + col] = f2b(acc[mg][ng][r]);
        } else if (colb < 5120) {  // K row-major (ld 1024)
#pragma unroll
          for (int r = 0; r < 4; r++)
            ((ushort_t*)C1)[(row0 + r) * 1024 + (col - 4096)] = f2b(acc[mg][ng][r]);
        } else {  // V -> 64-row MFMA-fragment-chunk layout
          const int ch = col - 5120;
          const int kvh = ch >> 8, chh = ch & 255, f = chh >> 4, lrv = chh & 15;
          const size_t bb = row0 >> 11;
          const int s0 = (int)(row0 & 2047);
          const int tile = s0 >> 6, kh = (s0 >> 5) & 1, lqv = (s0 >> 3) & 3, j0 = s0 & 7;
          ushort4v pk;
#pragma unroll
          for (int r = 0; r < 4; r++) pk[r] = f2b(acc[mg][ng][r]);
          *(ushort4v*)&((ushort_t*)C2)[((bb * KVH + kvh) * (S / 64) + tile) * 16384 +
                                       (size_t)(f * 2 + kh) * 512 +
                                       (size_t)(lqv * 16 + lrv) * 8 + j0] = pk;
        }
      }
    }
}

// ---------------------------------------------------------------- RMSNorm + RoPE + swizzle (K)
__global__ void k_norm_rope_k(const ushort_t* __restrict__ Kb, ushort_t* __restrict__ Kf,
                              const float* __restrict__ w, const float* __restrict__ tab) {
  __shared__ ushort_t t[64 * 264];  // rows padded +8
  const int lane = threadIdx.x & 63, wave = threadIdx.x >> 6;
  const int tile = blockIdx.x, kvh = blockIdx.y, b = blockIdx.z;
#pragma unroll
  for (int rr = 0; rr < 16; rr++) {
    const int row = wave * 16 + rr;
    const int s = tile * 64 + row;
    const ushort_t* p = Kb + ((size_t)(b * S + s) * KVH + kvh) * HD + lane * 4;
    ushort4v raw = *(const ushort4v*)p;
    *(ushort4v*)&t[row * 264 + lane * 4] = norm_rope_row(raw, w, tab, s, 1.0f, lane);
  }
  __syncthreads();
  ushort_t* dst = Kf + ((size_t)(b * KVH + kvh) * (S / 64) + tile) * 16384;
  const int lr = lane & 15, lq = lane >> 4;
#pragma unroll
  for (int q = 0; q < 8; q++) {
    const int c = wave * 8 + q;  // chunk, wave-uniform
    const int nt = c >> 3, ks = c & 7;
    ushort8v v = *(const ushort8v*)&t[(nt * 16 + lr) * 264 + ks * 32 + lq * 8];
    *(ushort8v*)&dst[(size_t)c * 512 + lane * 8] = v;
  }
}

// ---------------------------------------------------------------- flash attention
// r2-verified schedule (156 us): one __syncthreads pair per kv-tile, combined
// 16-load K+V staging, no split pipeline (r6/r7's split counted-vmcnt staging
// was +33 us of pure stall — reverted). Two orthogonal adds kept:
//  (a) XCD remap: 1-D grid 512 blocks; lin%8 -> (b,kvh) so each XCD's L2
//      holds its own 2MB KV slice (FETCH 107->46MB, verified r6).
//  (b) Q RMSNorm+RoPE fused into the Q-load (kills the k_norm_rope dispatch,
//      ~11 us + 67MB traffic; rotate-half partner qf[ks^4] is lane-local).
// Block does q-tiles {31-xq, xq} -> uniform 33 kv-tiles. 74.75KB LDS -> 2
// blocks/CU; launch_bounds(256,2).
__global__ __launch_bounds__(256, 2)
void k_attn(const ushort_t* __restrict__ Q, const ushort_t* __restrict__ Kf,
            const ushort_t* __restrict__ Vf, ushort_t* __restrict__ O,
            const float* __restrict__ qw, const float* __restrict__ tab) {
  __shared__ ushort_t Ks[32 * 512];   // chunks c = nt*8+ks, nt 0..3
  __shared__ ushort_t Vs[32 * 512];   // chunks (f*2+kh), f 0..15, kh 0..1
  __shared__ ushort_t Ps[4][16 * 72]; // per-wave P 16x64, row stride 72
  const int lane = threadIdx.x & 63, wave = threadIdx.x >> 6;
  const int lr = lane & 15, lq = lane >> 4;
  const int lin = blockIdx.x;          // 0..511
  const int g = lin & 7, j = lin >> 3; // g -> XCD -> (b,kvh); j 0..63
  const int b = g >> 2, kvh = g & 3;
  const int h = kvh * 4 + (j >> 4);
  const int xq = j & 15;
  const size_t kvb = (size_t)(b * KVH + kvh) * (S / 64);

#pragma unroll 1
  for (int half = 0; half < 2; half++) {
    const int qt = half ? xq : (S / 64 - 1 - xq);
    const int q0 = qt * 64 + wave * 16;
    const int sq = q0 + lr;

    // ---- fused RMSNorm + RoPE Q-load: qf[ks][jj] = Qn[sq][ks*32+lq*8+jj]
    bf16x8 qf[8];
    {
      const ushort_t* qp = Q + ((size_t)(b * S + sq) * H + h) * HD + lq * 8;
      ushort8v qr[8];
#pragma unroll
      for (int ks = 0; ks < 8; ks++) qr[ks] = *(const ushort8v*)(qp + ks * 32);
      float ss = 0.f;
#pragma unroll
      for (int ks = 0; ks < 8; ks++)
#pragma unroll
        for (int jj = 0; jj < 8; jj++) { float v = b2f(qr[ks][jj]); ss += v * v; }
      ss += __shfl_xor(ss, 16, 64);
      ss += __shfl_xor(ss, 32, 64);
      const float inv = rsqrtf(ss * (1.0f / HD) + 1e-6f);
      const float sc = 0.0625f * 1.4426950408889634f;  // 1/sqrt(HD) * log2(e)
#pragma unroll
      for (int c = 0; c < 4; c++) {
        const int d0 = c * 32 + lq * 8;  // 0..127
        float wl[8], wh[8];
        {
          float4 a0 = *(const float4*)(qw + d0);
          float4 a1 = *(const float4*)(qw + d0 + 4);
          float4 a2 = *(const float4*)(qw + d0 + 128);
          float4 a3 = *(const float4*)(qw + d0 + 132);
          wl[0]=a0.x; wl[1]=a0.y; wl[2]=a0.z; wl[3]=a0.w;
          wl[4]=a1.x; wl[5]=a1.y; wl[6]=a1.z; wl[7]=a1.w;
          wh[0]=a2.x; wh[1]=a2.y; wh[2]=a2.z; wh[3]=a2.w;
          wh[4]=a3.x; wh[5]=a3.y; wh[6]=a3.z; wh[7]=a3.w;
        }
        const float* tp = tab + ((size_t)sq * 128 + d0) * 2;
        ushort8v olo, ohi;
#pragma unroll
        for (int jj = 0; jj < 8; jj++) {
          float ylo = b2f(qr[c][jj]) * inv * (1.0f + wl[jj]);
          float yhi = b2f(qr[c + 4][jj]) * inv * (1.0f + wh[jj]);
          float2 cs = *(const float2*)(tp + jj * 2);
          olo[jj] = f2b((ylo * cs.x - yhi * cs.y) * sc);
          ohi[jj] = f2b((yhi * cs.x + ylo * cs.y) * sc);
        }
        qf[c] = *reinterpret_cast<bf16x8*>(&olo);
        qf[c + 4] = *reinterpret_cast<bf16x8*>(&ohi);
      }
    }

    floatx4 o[16];
#pragma unroll
    for (int f = 0; f < 16; f++) o[f] = {0.f, 0.f, 0.f, 0.f};
    float m_i[4] = {-1e30f, -1e30f, -1e30f, -1e30f};
    float l_i[4] = {0.f, 0.f, 0.f, 0.f};

    const int ntiles = qt + 1;
    for (int kt = 0; kt < ntiles; kt++) {
      const int kbase = kt * 64;
      __syncthreads();  // previous tile's LDS reads done
      const ushort_t* tb = Kf + (kvb + kt) * 16384;
      const ushort_t* vb = Vf + (kvb + kt) * 16384;
#pragma unroll
      for (int i = 0; i < 16; i++) {
        const int c = wave * 16 + i;
        if (c < 32) gll16(tb + (size_t)c * 512 + lane * 8, &Ks[c * 512 + lane * 8]);
        else        gll16(vb + (size_t)(c - 32) * 512 + lane * 8, &Vs[(c - 32) * 512 + lane * 8]);
      }
      __syncthreads();  // staging drained

      const int ntmax = min(4, ((q0 + 15 - kbase) >> 4) + 1);  // >= 1 always
      floatx4 sacc[4];
#pragma unroll
      for (int nt = 0; nt < 4; nt++) {
        if (nt < ntmax) {
          sacc[nt] = {0.f, 0.f, 0.f, 0.f};
#pragma unroll
          for (int ks = 0; ks < 8; ks++) {
            bf16x8 kf = *(const bf16x8*)&Ks[(nt * 8 + ks) * 512 + lane * 8];
            sacc[nt] = __builtin_amdgcn_mfma_f32_16x16x32_bf16(qf[ks], kf, sacc[nt], 0, 0, 0);
          }
        } else {
          sacc[nt] = {-1e30f, -1e30f, -1e30f, -1e30f};
        }
      }
      if (kbase + 63 > q0) {  // causal mask on diagonal tiles
#pragma unroll
        for (int nt = 0; nt < 4; nt++)
          if (nt < ntmax)
#pragma unroll
            for (int r = 0; r < 4; r++)
              if (kbase + nt * 16 + lr > q0 + lq * 4 + r) sacc[nt][r] = -1e30f;
      }
      float mt[4], alpha[4], rs[4];
#pragma unroll
      for (int r = 0; r < 4; r++)
        mt[r] = fmaxf(fmaxf(sacc[0][r], sacc[1][r]), fmaxf(sacc[2][r], sacc[3][r]));
#pragma unroll
      for (int m = 1; m < 16; m <<= 1)
#pragma unroll
        for (int r = 0; r < 4; r++) mt[r] = fmaxf(mt[r], __shfl_xor(mt[r], m, 64));
#pragma unroll
      for (int r = 0; r < 4; r++) {
        float mn = fmaxf(m_i[r], mt[r]);
        alpha[r] = exp2f(m_i[r] - mn);
        m_i[r] = mn;
      }
#pragma unroll
      for (int nt = 0; nt < 4; nt++)
#pragma unroll
        for (int r = 0; r < 4; r++) sacc[nt][r] = exp2f(sacc[nt][r] - m_i[r]);
#pragma unroll
      for (int r = 0; r < 4; r++)
        rs[r] = (sacc[0][r] + sacc[1][r]) + (sacc[2][r] + sacc[3][r]);
#pragma unroll
      for (int m = 1; m < 16; m <<= 1)
#pragma unroll
        for (int r = 0; r < 4; r++) rs[r] += __shfl_xor(rs[r], m, 64);
#pragma unroll
      for (int r = 0; r < 4; r++) l_i[r] = l_i[r] * alpha[r] + rs[r];
      // skip the 64-mul rescale when no row's max changed (common in steady state)
      if (__any((alpha[0] < 1.f) | (alpha[1] < 1.f) | (alpha[2] < 1.f) | (alpha[3] < 1.f))) {
#pragma unroll
        for (int f = 0; f < 16; f++) {
          o[f][0] *= alpha[0]; o[f][1] *= alpha[1];
          o[f][2] *= alpha[2]; o[f][3] *= alpha[3];
        }
      }
      ushort_t* psw = Ps[wave];
#pragma unroll
      for (int nt = 0; nt < 4; nt++)
#pragma unroll
        for (int r = 0; r < 4; r++)
          psw[(lq * 4 + r) * 72 + nt * 16 + lr] = f2b(sacc[nt][r]);
      bf16x8 pf0 = *(const bf16x8*)&psw[lr * 72 + lq * 8];
      bf16x8 pf1 = *(const bf16x8*)&psw[lr * 72 + 32 + lq * 8];
#pragma unroll
      for (int f = 0; f < 16; f++) {
        bf16x8 vf0 = *(const bf16x8*)&Vs[(f * 2 + 0) * 512 + lane * 8];
        o[f] = __builtin_amdgcn_mfma_f32_16x16x32_bf16(pf0, vf0, o[f], 0, 0, 0);
        bf16x8 vf1 = *(const bf16x8*)&Vs[(f * 2 + 1) * 512 + lane * 8];
        o[f] = __builtin_amdgcn_mfma_f32_16x16x32_bf16(pf1, vf1, o[f], 0, 0, 0);
      }
    }
    float invl[4];
#pragma unroll
    for (int r = 0; r < 4; r++) invl[r] = 1.0f / l_i[r];
#pragma unroll
    for (int f = 0; f < 16; f++)
#pragma unroll
      for (int r = 0; r < 4; r++)
        O[((size_t)(b * S + q0 + lq * 4 + r) * H + h) * HD + f * 16 + lr] =
            f2b(o[f][r] * invl[r]);
  }
}

// ---------------------------------------------------------------- launch
extern "C" void kernel_launch(void* const* d_in, const int* in_sizes, int n_in,
                              void* d_out, int out_size, void* d_ws, size_t ws_size,
                              hipStream_t stream) {
  const float* hs = (const float*)d_in[0];
  const float* Wq = (const float*)d_in[1];
  const float* Wk = (const float*)d_in[2];
  const float* Wv = (const float*)d_in[3];
  const float* Wo = (const float*)d_in[4];
  const float* qw = (const float*)d_in[5];
  const float* kw = (const float*)d_in[6];
  const int* pos = (const int*)d_in[7];
  float* out = (float*)d_out;

  char* ws = (char*)d_ws;
  size_t off = 0;
  auto alloc = [&](size_t bytes) {
    void* p = ws + off;
    off += (bytes + 255) & ~(size_t)255;
    return p;
  };
  ushort_t* Xb   = (ushort_t*)alloc((size_t)B * S * D * 2);
  // Wqt and Wkvt MUST stay adjacent: fused QKV GEMM treats them as one
  // 6144 x 2048 Bt matrix (Wq^T rows [0,4096), Wk^T [4096,5120), Wv^T [5120,6144)).
  ushort_t* Wqt  = (ushort_t*)alloc((size_t)(H * HD) * D * 2);
  ushort_t* Wkvt = (ushort_t*)alloc((size_t)(2 * KVH * HD) * D * 2);
  ushort_t* Wot  = (ushort_t*)alloc((size_t)D * (H * HD) * 2);
  ushort_t* Qb   = (ushort_t*)alloc((size_t)B * S * H * HD * 2);
  ushort_t* Kf   = (ushort_t*)alloc((size_t)B * S * KVH * HD * 2);
  ushort_t* Vf   = (ushort_t*)alloc((size_t)B * S * KVH * HD * 2);
  ushort_t* Ab   = (ushort_t*)alloc((size_t)B * S * H * HD * 2);
  float*    tab  = (float*)alloc((size_t)S * 128 * 2 * sizeof(float));
  ushort_t* Kb = Ab;  // aliased: consumed by k_norm_rope_k before k_attn writes Ab

  k_cvt_bf16<<<(B * S * D / 4 + 255) / 256, 256, 0, stream>>>(hs, Xb, B * S * D);
  k_transpose_cvt<<<dim3((H * HD) / 64, D / 64), 256, 0, stream>>>(Wq, Wqt, D, H * HD);
  k_transpose_cvt<<<dim3((KVH * HD) / 64, D / 64), 256, 0, stream>>>(Wk, Wkvt, D, KVH * HD);
  k_transpose_cvt<<<dim3((KVH * HD) / 64, D / 64), 256, 0, stream>>>(
      Wv, Wkvt + (size_t)(KVH * HD) * D, D, KVH * HD);
  k_transpose_cvt<<<dim3(D / 64, (H * HD) / 64), 256, 0, stream>>>(Wo, Wot, H * HD, D);
  k_rope_table<<<S * 128 / 256, 256, 0, stream>>>(pos, tab);

  // fused Q+K+V projection: N = 4096 + 1024 + 1024 = 6144; 32x24 = 768 blocks = 3 exact rounds
  k_gemm256<0><<<dim3((B * S) / 128, 6144 / 256), 512, 0, stream>>>(
      Xb, Wqt, Qb, Kb, Vf, 6144, D);

  k_norm_rope_k<<<dim3(S / 64, KVH, B), 256, 0, stream>>>(Kb, Kf, kw, tab);

  // Q norm+rope fused into k_attn; 512 blocks = one round at 2 blocks/CU
  k_attn<<<512, 256, 0, stream>>>(Qb, Kf, Vf, Ab, qw, tab);

  // O-projection: 32x8 = 256 blocks = exactly one full round
  k_gemm256<1><<<dim3((B * S) / 128, D / 256), 512, 0, stream>>>(
      Ab, Wot, out, nullptr, nullptr, D, H * HD);
}